// Round 4
// baseline (220.554 us; speedup 1.0000x reference)
//
#include <hip/hip_runtime.h>
#include <math.h>

// NGRU via MFMA, R4. Only layer 1 of the 2 parallel GRU layers contributes
// (reference returns h_final[-1]); layer 0 is skipped.
//
// Shapes: x (64,48,256,64) f32; Wih/Whh (2,192,64); bih/bhh (2,192).
// rows = B*N = 16384 independent GRU sequences, T=48, H=64.
//
// R4 structure: 1024 blocks x 256 threads (4 waves), 16 rows/block,
// target 4 blocks/CU (4 independent barrier domains -> phase overlap;
// LDS 17.5 KB/block). Wave nw owns output columns j in [16nw,16nw+16) for
// ALL FOUR gates (g=0:r, 1:z, 2:gin, 3:ghn) -> gate epilogue fully
// register-local. Zero B-tiles skipped: 12 kt-slots, 36 MFMA/wave/step.
//
// A = [x_t | h_{t-1}] bf16 hi/lo planes, ping-ponged -> ONE barrier/step.
// R4 fixes the R3 bank bug: lo-plane stagger is now +16 shorts == +8 banks
// (PLANE = 16*136+16), so the paired h dword writes (even lane -> hi plane,
// odd lane -> lo plane) cover all 32 banks 2-way = free.
// All f32->bf16 conversion uses v_cvt_pk_bf16_f32 (1 instr per 2 values,
// RNE -> bit-identical to the old 5-op scalar path).
//
// Split-bf16: v = hi + lo; product = AhBh + AhBl + AlBh (~2^-17 rel), same
// accumulation order as R3 -> bit-identical numerics.

#define TT 48
#define HH 64
#define GG 192
#define NN 256
#define RPB 16          // rows per block
#define NTHREADS 256    // 4 waves
#define AK 136          // A row stride in shorts (128 + 8 pad)
#define PLANE 2192      // shorts per plane (16*136 + 16 stagger = +8 banks)
#define ABUF (2*PLANE)  // shorts per A buffer (hi+lo)

typedef __attribute__((ext_vector_type(8))) short bs8;     // 8 bf16
typedef __attribute__((ext_vector_type(4))) float f32x4;   // MFMA accum

__device__ __forceinline__ float sigm(float v) {
    return __builtin_amdgcn_rcpf(1.f + __expf(-v));
}
__device__ __forceinline__ float tanh_f(float v) {
    float a = fabsf(v);
    float e = __expf(2.f * a);
    float t = 1.f - 2.f * __builtin_amdgcn_rcpf(e + 1.f);
    return v < 0.f ? -t : t;
}
// packed f32x2 -> bf16x2 (RNE): D[15:0]=bf16(S0), D[31:16]=bf16(S1)
__device__ __forceinline__ unsigned cvtpk(float lo, float hi) {
    unsigned r;
    asm("v_cvt_pk_bf16_f32 %0, %1, %2" : "=v"(r) : "v"(lo), "v"(hi));
    return r;
}
__device__ __forceinline__ float ubits(unsigned u) { return __uint_as_float(u); }
// scalar RNE helpers (B build only; one-time)
__device__ __forceinline__ unsigned short f2bf(float f) {
    unsigned u = __float_as_uint(f);
    return (unsigned short)((u + 0x7fffu + ((u >> 16) & 1u)) >> 16);
}
__device__ __forceinline__ float bf2f(unsigned short b) {
    return __uint_as_float(((unsigned)b) << 16);
}

__global__ __launch_bounds__(NTHREADS, 4)
void ngru_mfma4(const float* __restrict__ x,
                const float* __restrict__ Wih,
                const float* __restrict__ Whh,
                const float* __restrict__ bih,
                const float* __restrict__ bhh,
                float* __restrict__ out)
{
    extern __shared__ __align__(16) short lds_s[];   // 2 x ABUF shorts

    const int tid  = threadIdx.x;
    const int lane = tid & 63;
    const int nw   = tid >> 6;          // wave 0..3 -> j slice [16nw,16nw+16)
    const int c0   = lane & 15;         // C col within tile / A row index
    const int rq   = lane >> 4;         // quarter-wave
    const int j    = nw * 16 + c0;
    const bool odd = (c0 & 1);

    const int grow0 = blockIdx.x * RPB;
    const int bb    = grow0 / NN;
    const int n0    = grow0 % NN;

    const float* Wi = Wih + GG * HH;    // layer 1
    const float* Wh = Whh + GG * HH;

    // ---- B fragments in registers: 12 kt-slots (zero tiles skipped) ----
    bs8 Bh[12], Bl[12];
    #pragma unroll
    for (int g = 0; g < 4; ++g) {
        const int ktlo = (g == 3) ? 2 : 0;
        const int kthi = (g == 2) ? 2 : 4;
        #pragma unroll
        for (int kt = ktlo; kt < kthi; ++kt) {
            const int slot = (g < 2) ? g * 4 + kt : 8 + (g - 2) * 2 + (kt & 1);
            const bool isWi = (kt < 2);
            const int gbase = (g >= 2) ? 2 : g;
            const float* src = (isWi ? Wi : Wh)
                             + (gbase * 64 + j) * HH + (kt & 1) * 32 + rq * 8;
            bs8 h8, l8;
            #pragma unroll
            for (int q = 0; q < 8; ++q) {
                float v = src[q];
                unsigned short hb = f2bf(v);
                unsigned short lb = f2bf(v - bf2f(hb));
                h8[q] = (short)hb; l8[q] = (short)lb;
            }
            Bh[slot] = h8; Bl[slot] = l8;
        }
    }

    // ---- biases (layer 1), r/z pre-summed; n biases stay separate ----
    const float brz  = bih[GG + j]      + bhh[GG + j];
    const float bzz  = bih[GG + 64 + j] + bhh[GG + 64 + j];
    const float bi_n = bih[GG + 128 + j];
    const float bh_n = bhh[GG + 128 + j];

    // ---- init buf0: zero h region, stage x_0 ----
    const int xrow = tid >> 4;          // 0..15
    const int xc   = (tid & 15) * 4;    // elem/short offset 0,4,...,60
    {
        // zero h region (both planes), 8B per thread per plane
        *(uint2*)(lds_s + xrow * AK + 64 + xc)         = (uint2){0u, 0u};
        *(uint2*)(lds_s + PLANE + xrow * AK + 64 + xc) = (uint2){0u, 0u};

        const float* xsrc = x + ((size_t)(bb * TT) * NN + n0 + xrow) * HH + xc;
        float4 p = *(const float4*)xsrc;
        unsigned h0 = cvtpk(p.x, p.y), h1 = cvtpk(p.z, p.w);
        float r0 = p.x - ubits(h0 << 16), r1 = p.y - ubits(h0 & 0xffff0000u);
        float r2 = p.z - ubits(h1 << 16), r3 = p.w - ubits(h1 & 0xffff0000u);
        unsigned l0 = cvtpk(r0, r1), l1 = cvtpk(r2, r3);
        *(uint2*)(lds_s + xrow * AK + xc)         = (uint2){h0, h1};
        *(uint2*)(lds_s + PLANE + xrow * AK + xc) = (uint2){l0, l1};
    }

    float hreg[4];
    #pragma unroll
    for (int r = 0; r < 4; ++r) hreg[r] = 0.f;

    __syncthreads();   // buf0 ready for t=0

    for (int t = 0; t < TT; ++t) {
        short* cur = lds_s + (t & 1) * ABUF;
        short* nxt = lds_s + ((t & 1) ^ 1) * ABUF;

        // prefetch x_{t+1} (HBM latency hides under MFMA + epilogue)
        float4 p;
        const bool hasNext = (t + 1 < TT);
        if (hasNext) {
            const float* xsrc =
                x + ((size_t)(bb * TT + t + 1) * NN + n0 + xrow) * HH + xc;
            p = *(const float4*)xsrc;
        }

        // ===== MFMA: 4 gate-tiles, kt-outer (A liveness = 8 regs) =====
        f32x4 acc[4];
        #pragma unroll
        for (int g = 0; g < 4; ++g) acc[g] = (f32x4){0.f, 0.f, 0.f, 0.f};

        const short* ab = cur + c0 * AK + rq * 8;
        __builtin_amdgcn_s_setprio(1);
        #pragma unroll
        for (int kt = 0; kt < 4; ++kt) {
            bs8 Ah = *(const bs8*)(ab + kt * 32);
            bs8 Al = *(const bs8*)(ab + PLANE + kt * 32);
            const int s0 = kt;                                   // gate r
            const int s1 = 4 + kt;                               // gate z
            const int s2 = (kt < 2) ? (8 + kt) : (10 + (kt & 1)); // gin/ghn
            const int g2 = (kt < 2) ? 2 : 3;
            acc[0] = __builtin_amdgcn_mfma_f32_16x16x32_bf16(Ah, Bh[s0], acc[0], 0, 0, 0);
            acc[0] = __builtin_amdgcn_mfma_f32_16x16x32_bf16(Ah, Bl[s0], acc[0], 0, 0, 0);
            acc[0] = __builtin_amdgcn_mfma_f32_16x16x32_bf16(Al, Bh[s0], acc[0], 0, 0, 0);
            acc[1] = __builtin_amdgcn_mfma_f32_16x16x32_bf16(Ah, Bh[s1], acc[1], 0, 0, 0);
            acc[1] = __builtin_amdgcn_mfma_f32_16x16x32_bf16(Ah, Bl[s1], acc[1], 0, 0, 0);
            acc[1] = __builtin_amdgcn_mfma_f32_16x16x32_bf16(Al, Bh[s1], acc[1], 0, 0, 0);
            acc[g2] = __builtin_amdgcn_mfma_f32_16x16x32_bf16(Ah, Bh[s2], acc[g2], 0, 0, 0);
            acc[g2] = __builtin_amdgcn_mfma_f32_16x16x32_bf16(Ah, Bl[s2], acc[g2], 0, 0, 0);
            acc[g2] = __builtin_amdgcn_mfma_f32_16x16x32_bf16(Al, Bh[s2], acc[g2], 0, 0, 0);
        }
        __builtin_amdgcn_s_setprio(0);

        // ===== epilogue: register-local gates; h -> nxt buffer =====
        short* hp = nxt + (odd ? PLANE : 0);
        #pragma unroll
        for (int r = 0; r < 4; ++r) {
            const int row = rq * 4 + r;
            float sr  = acc[0][r] + brz;
            float sz  = acc[1][r] + bzz;
            float gin = acc[2][r] + bi_n;
            float ghn = acc[3][r] + bh_n;
            float rg = sigm(sr);
            float zg = sigm(sz);
            float ng = tanh_f(fmaf(rg, ghn, gin));
            float hn = fmaf(zg, hreg[r] - ng, ng);   // (1-z)n + z h
            hreg[r] = hn;
            // paired dword write: even lane -> hi-plane dword {j, j+1},
            // odd lane -> lo-plane dword; planes staggered 8 banks -> 2-way
            float partner = __shfl_xor(hn, 1);
            float ve = odd ? partner : hn;     // value at even column
            float vo = odd ? hn : partner;     // value at odd column
            unsigned hd = cvtpk(ve, vo);
            float re = ve - ubits(hd << 16);
            float ro = vo - ubits(hd & 0xffff0000u);
            unsigned ld = cvtpk(re, ro);
            unsigned w = odd ? ld : hd;
            *(unsigned*)(hp + row * AK + 64 + (j & ~1)) = w;
        }

        if (hasNext) {
            unsigned h0 = cvtpk(p.x, p.y), h1 = cvtpk(p.z, p.w);
            float r0 = p.x - ubits(h0 << 16), r1 = p.y - ubits(h0 & 0xffff0000u);
            float r2 = p.z - ubits(h1 << 16), r3 = p.w - ubits(h1 & 0xffff0000u);
            unsigned l0 = cvtpk(r0, r1), l1 = cvtpk(r2, r3);
            *(uint2*)(nxt + xrow * AK + xc)         = (uint2){h0, h1};
            *(uint2*)(nxt + PLANE + xrow * AK + xc) = (uint2){l0, l1};
            __syncthreads();   // nxt (h_t + x_{t+1}) ready for step t+1
        }
    }

    #pragma unroll
    for (int r = 0; r < 4; ++r)
        out[(size_t)(grow0 + rq * 4 + r) * HH + j] = hreg[r];
}

extern "C" void kernel_launch(void* const* d_in, const int* in_sizes, int n_in,
                              void* d_out, int out_size, void* d_ws, size_t ws_size,
                              hipStream_t stream) {
    const float* x   = (const float*)d_in[0];
    const float* Wih = (const float*)d_in[1];
    const float* Whh = (const float*)d_in[2];
    const float* bih = (const float*)d_in[3];
    const float* bhh = (const float*)d_in[4];
    float* out = (float*)d_out;

    const int lds_bytes = 2 * ABUF * (int)sizeof(short);   // 17,536 B
    (void)hipFuncSetAttribute((const void*)ngru_mfma4,
                        hipFuncAttributeMaxDynamicSharedMemorySize, lds_bytes);

    dim3 grid(16384 / RPB);     // 1024 blocks, up to 4 per CU
    dim3 block(NTHREADS);
    ngru_mfma4<<<grid, block, lds_bytes, stream>>>(x, Wih, Whh, bih, bhh, out);
}

// Round 5
// 117.452 us; speedup vs baseline: 1.8778x; 1.8778x over previous
//
#include <hip/hip_runtime.h>
#include <math.h>

// NGRU via MFMA, R5 = R3 structure + verified R4 micro-fixes.
// Only layer 1 of the 2 parallel GRU layers contributes (reference returns
// h_final[-1]); layer 0 is skipped.
//
// Shapes: x (64,48,256,64) f32; Wih/Whh (2,192,64); bih/bhh (2,192).
// rows = B*N = 16384 independent GRU sequences, T=48, H=64.
//
// Structure: 512 blocks x 256 threads (4 waves), 32 rows/block, 2 blocks/CU
// (launch_bounds(256,2): R4 proved forcing 4 waves/EU spills the 96-VGPR
// B-fragment set -> 128MB scratch traffic; don't cap below ~160).
// Wave nw owns output columns j in [16nw,16nw+16) for ALL FOUR gates
// (g=0:r, 1:z, 2:gin, 3:ghn) -> gate epilogue fully register-local.
// Zero B-tiles skipped: 12 kt-slots, 72 MFMA/wave/step.
//
// A = [x_t | h_{t-1}] bf16 hi/lo planes, ping-ponged -> ONE barrier/step.
// Bank fix vs R3: lo-plane stagger is +16 shorts == +8 banks (PLANE =
// 32*136+16 = 4368), so paired h dword writes (even lane -> hi plane, odd
// lane -> lo plane) cover all 32 banks 2-way = free. (R3's +32-short
// stagger aliased hi/lo onto the same 16 banks -> 4-way, 7.8M conflict cyc.)
// All steady-state f32->bf16 uses v_cvt_pk_bf16_f32 (RNE, bit-identical to
// the scalar path -- verified in R4).
//
// Split-bf16: v = hi + lo; product = AhBh + AhBl + AlBh (~2^-17 rel), same
// accumulation order as R3 -> bit-identical numerics.

#define TT 48
#define HH 64
#define GG 192
#define NN 256
#define RPB 32          // rows per block
#define NTHREADS 256    // 4 waves
#define AK 136          // A row stride in shorts (128 + 8 pad)
#define PLANE 4368      // shorts per plane (32*136 + 16 stagger = +8 banks)
#define ABUF (2*PLANE)  // shorts per A buffer (hi+lo)

typedef __attribute__((ext_vector_type(8))) short bs8;     // 8 bf16
typedef __attribute__((ext_vector_type(4))) float f32x4;   // MFMA accum

__device__ __forceinline__ float sigm(float v) {
    return __builtin_amdgcn_rcpf(1.f + __expf(-v));
}
__device__ __forceinline__ float tanh_f(float v) {
    float a = fabsf(v);
    float e = __expf(2.f * a);
    float t = 1.f - 2.f * __builtin_amdgcn_rcpf(e + 1.f);
    return v < 0.f ? -t : t;
}
// packed f32x2 -> bf16x2 (RNE): D[15:0]=bf16(S0), D[31:16]=bf16(S1)
__device__ __forceinline__ unsigned cvtpk(float lo, float hi) {
    unsigned r;
    asm("v_cvt_pk_bf16_f32 %0, %1, %2" : "=v"(r) : "v"(lo), "v"(hi));
    return r;
}
__device__ __forceinline__ float ubits(unsigned u) { return __uint_as_float(u); }
// scalar RNE helpers (one-time B build only)
__device__ __forceinline__ unsigned short f2bf(float f) {
    unsigned u = __float_as_uint(f);
    return (unsigned short)((u + 0x7fffu + ((u >> 16) & 1u)) >> 16);
}
__device__ __forceinline__ float bf2f(unsigned short b) {
    return __uint_as_float(((unsigned)b) << 16);
}

__global__ __launch_bounds__(NTHREADS, 2)
void ngru_mfma5(const float* __restrict__ x,
                const float* __restrict__ Wih,
                const float* __restrict__ Whh,
                const float* __restrict__ bih,
                const float* __restrict__ bhh,
                float* __restrict__ out)
{
    extern __shared__ __align__(16) short lds_s[];   // 2 x ABUF shorts

    const int tid  = threadIdx.x;
    const int lane = tid & 63;
    const int nw   = tid >> 6;          // wave 0..3 -> j slice [16nw,16nw+16)
    const int c0   = lane & 15;         // C col within tile / A row index
    const int rq   = lane >> 4;         // quarter-wave
    const int j    = nw * 16 + c0;
    const bool odd = (c0 & 1);

    const int grow0 = blockIdx.x * RPB;
    const int bb    = grow0 / NN;
    const int n0    = grow0 % NN;

    const float* Wi = Wih + GG * HH;    // layer 1
    const float* Wh = Whh + GG * HH;

    // ---- B fragments in registers: 12 kt-slots (zero tiles skipped) ----
    bs8 Bh[12], Bl[12];
    #pragma unroll
    for (int g = 0; g < 4; ++g) {
        const int ktlo = (g == 3) ? 2 : 0;
        const int kthi = (g == 2) ? 2 : 4;
        #pragma unroll
        for (int kt = ktlo; kt < kthi; ++kt) {
            const int slot = (g < 2) ? g * 4 + kt : 8 + (g - 2) * 2 + (kt & 1);
            const bool isWi = (kt < 2);
            const int gbase = (g >= 2) ? 2 : g;
            const float* src = (isWi ? Wi : Wh)
                             + (gbase * 64 + j) * HH + (kt & 1) * 32 + rq * 8;
            bs8 h8, l8;
            #pragma unroll
            for (int q = 0; q < 8; ++q) {
                float v = src[q];
                unsigned short hb = f2bf(v);
                unsigned short lb = f2bf(v - bf2f(hb));
                h8[q] = (short)hb; l8[q] = (short)lb;
            }
            Bh[slot] = h8; Bl[slot] = l8;
        }
    }

    // ---- biases (layer 1), r/z pre-summed; n biases stay separate ----
    const float brz  = bih[GG + j]      + bhh[GG + j];
    const float bzz  = bih[GG + 64 + j] + bhh[GG + 64 + j];
    const float bi_n = bih[GG + 128 + j];
    const float bh_n = bhh[GG + 128 + j];

    // ---- init buf0: zero h region, stage x_0 ----
    const int xrow = tid >> 3;          // 0..31
    const int xkc  = (tid & 7) * 8;     // short offset 0,8,...,56
    {
        bs8 z = {0,0,0,0,0,0,0,0};
        *(bs8*)(lds_s + xrow * AK + 64 + xkc)         = z;
        *(bs8*)(lds_s + PLANE + xrow * AK + 64 + xkc) = z;

        const float* xsrc = x + ((size_t)(bb * TT) * NN + n0 + xrow) * HH + xkc;
        float4 p0 = *(const float4*)xsrc;
        float4 p1 = *(const float4*)(xsrc + 4);
        unsigned h0 = cvtpk(p0.x, p0.y), h1 = cvtpk(p0.z, p0.w);
        unsigned h2 = cvtpk(p1.x, p1.y), h3 = cvtpk(p1.z, p1.w);
        unsigned l0 = cvtpk(p0.x - ubits(h0 << 16), p0.y - ubits(h0 & 0xffff0000u));
        unsigned l1 = cvtpk(p0.z - ubits(h1 << 16), p0.w - ubits(h1 & 0xffff0000u));
        unsigned l2 = cvtpk(p1.x - ubits(h2 << 16), p1.y - ubits(h2 & 0xffff0000u));
        unsigned l3 = cvtpk(p1.z - ubits(h3 << 16), p1.w - ubits(h3 & 0xffff0000u));
        *(uint4*)(lds_s + xrow * AK + xkc)         = (uint4){h0, h1, h2, h3};
        *(uint4*)(lds_s + PLANE + xrow * AK + xkc) = (uint4){l0, l1, l2, l3};
    }

    float hreg[2][4];
    #pragma unroll
    for (int m = 0; m < 2; ++m)
        #pragma unroll
        for (int r = 0; r < 4; ++r) hreg[m][r] = 0.f;

    __syncthreads();   // buf0 ready for t=0

    for (int t = 0; t < TT; ++t) {
        short* cur = lds_s + (t & 1) * ABUF;
        short* nxt = lds_s + ((t & 1) ^ 1) * ABUF;

        // prefetch x_{t+1} early (HBM latency hides under MFMA+epilogue)
        float4 p0, p1;
        const bool hasNext = (t + 1 < TT);
        if (hasNext) {
            const float* xsrc =
                x + ((size_t)(bb * TT + t + 1) * NN + n0 + xrow) * HH + xkc;
            p0 = *(const float4*)xsrc;
            p1 = *(const float4*)(xsrc + 4);
        }

        // ===== MFMA: 4 gate-tiles x 2 m-tiles, all gates land in-lane =====
        f32x4 acc[2][4];
        #pragma unroll
        for (int m = 0; m < 2; ++m)
            #pragma unroll
            for (int g = 0; g < 4; ++g)
                acc[m][g] = (f32x4){0.f, 0.f, 0.f, 0.f};

        __builtin_amdgcn_s_setprio(1);
        #pragma unroll
        for (int m = 0; m < 2; ++m) {
            const short* ab = cur + (m * 16 + c0) * AK + rq * 8;
            bs8 Ah_[4], Al_[4];
            #pragma unroll
            for (int kt = 0; kt < 4; ++kt) {
                Ah_[kt] = *(const bs8*)(ab + kt * 32);
                Al_[kt] = *(const bs8*)(ab + PLANE + kt * 32);
            }
            #pragma unroll
            for (int g = 0; g < 4; ++g) {
                #pragma unroll
                for (int kt = 0; kt < 4; ++kt) {
                    if ((g == 2 && kt >= 2) || (g == 3 && kt < 2)) continue;
                    const int slot = (g < 2) ? g * 4 + kt
                                             : 8 + (g - 2) * 2 + (kt & 1);
                    acc[m][g] = __builtin_amdgcn_mfma_f32_16x16x32_bf16(
                        Ah_[kt], Bh[slot], acc[m][g], 0, 0, 0);
                    acc[m][g] = __builtin_amdgcn_mfma_f32_16x16x32_bf16(
                        Ah_[kt], Bl[slot], acc[m][g], 0, 0, 0);
                    acc[m][g] = __builtin_amdgcn_mfma_f32_16x16x32_bf16(
                        Al_[kt], Bh[slot], acc[m][g], 0, 0, 0);
                }
            }
        }
        __builtin_amdgcn_s_setprio(0);

        // ===== epilogue: register-local gates; h -> nxt buffer =====
        short* hp = nxt + (odd ? PLANE : 0);
        #pragma unroll
        for (int m = 0; m < 2; ++m) {
            #pragma unroll
            for (int r = 0; r < 4; ++r) {
                const int row = m * 16 + rq * 4 + r;
                float sr  = acc[m][0][r] + brz;
                float sz  = acc[m][1][r] + bzz;
                float gin = acc[m][2][r] + bi_n;
                float ghn = acc[m][3][r] + bh_n;
                float rg = sigm(sr);
                float zg = sigm(sz);
                float ng = tanh_f(fmaf(rg, ghn, gin));
                float hn = fmaf(zg, hreg[m][r] - ng, ng);   // (1-z)n + z h
                hreg[m][r] = hn;
                if (hasNext) {
                    // paired dword write: even lane -> hi-plane dword {j,j+1},
                    // odd lane -> lo-plane dword; planes staggered 8 banks
                    // -> combined 64-lane write covers 32 banks 2-way (free)
                    float partner = __shfl_xor(hn, 1);
                    float ve = odd ? partner : hn;     // value at even column
                    float vo = odd ? hn : partner;     // value at odd column
                    unsigned hd = cvtpk(ve, vo);
                    float re = ve - ubits(hd << 16);
                    float ro = vo - ubits(hd & 0xffff0000u);
                    unsigned ld = cvtpk(re, ro);
                    unsigned w = odd ? ld : hd;
                    *(unsigned*)(hp + row * AK + 64 + (j & ~1)) = w;
                }
            }
        }

        if (hasNext) {
            unsigned h0 = cvtpk(p0.x, p0.y), h1 = cvtpk(p0.z, p0.w);
            unsigned h2 = cvtpk(p1.x, p1.y), h3 = cvtpk(p1.z, p1.w);
            unsigned l0 = cvtpk(p0.x - ubits(h0 << 16), p0.y - ubits(h0 & 0xffff0000u));
            unsigned l1 = cvtpk(p0.z - ubits(h1 << 16), p0.w - ubits(h1 & 0xffff0000u));
            unsigned l2 = cvtpk(p1.x - ubits(h2 << 16), p1.y - ubits(h2 & 0xffff0000u));
            unsigned l3 = cvtpk(p1.z - ubits(h3 << 16), p1.w - ubits(h3 & 0xffff0000u));
            *(uint4*)(nxt + xrow * AK + xkc)         = (uint4){h0, h1, h2, h3};
            *(uint4*)(nxt + PLANE + xrow * AK + xkc) = (uint4){l0, l1, l2, l3};
            __syncthreads();   // nxt (h_t + x_{t+1}) ready for step t+1
        }
    }

    #pragma unroll
    for (int m = 0; m < 2; ++m)
        #pragma unroll
        for (int r = 0; r < 4; ++r)
            out[(size_t)(grow0 + m * 16 + rq * 4 + r) * HH + j] = hreg[m][r];
}

extern "C" void kernel_launch(void* const* d_in, const int* in_sizes, int n_in,
                              void* d_out, int out_size, void* d_ws, size_t ws_size,
                              hipStream_t stream) {
    const float* x   = (const float*)d_in[0];
    const float* Wih = (const float*)d_in[1];
    const float* Whh = (const float*)d_in[2];
    const float* bih = (const float*)d_in[3];
    const float* bhh = (const float*)d_in[4];
    float* out = (float*)d_out;

    const int lds_bytes = 2 * ABUF * (int)sizeof(short);   // 34,944 B
    (void)hipFuncSetAttribute((const void*)ngru_mfma5,
                        hipFuncAttributeMaxDynamicSharedMemorySize, lds_bytes);

    dim3 grid(16384 / RPB);     // 512 blocks, 2 per CU
    dim3 block(NTHREADS);
    ngru_mfma5<<<grid, block, lds_bytes, stream>>>(x, Wih, Whh, bih, bhh, out);
}